// Round 1
// baseline (955.368 us; speedup 1.0000x reference)
//
#include <hip/hip_runtime.h>

// ---------------------------------------------------------------------------
// VGAE encoder, MI355X. Strategy: the two adj (16384x16384 f32, 1 GiB) GEMMs
// dominate. fp32 has no MFMA on CDNA4 -> split each f32 into bf16 hi+lo and
// compute 3 MFMA terms (hi*hi + hi*lo + lo*hi): ~2^-18 relative error, fp32
// accumulate. Memory floor = 2 adj passes = ~340us @ 6.3 TB/s.
// B-operands (the skinny [16384][128] matrices) are pre-split and stored in a
// fragment layout so the big kernel loads them L2->registers fully coalesced;
// LDS carries only the adj tile (XOR-swizzled, double-buffered).
// ---------------------------------------------------------------------------

typedef __bf16 bf16_t;
typedef __attribute__((ext_vector_type(8))) __bf16 bf16x8;
typedef __attribute__((ext_vector_type(16))) float f32x16;

#define N_NODES 16384

// Fragment layout for the B operand of mfma_f32_32x32x16_bf16:
// element (k=r, col=c) -> 1KiB units indexed by (K16 = r>>4, cblk = c>>5),
// within a unit: lane = (c&31) + 32*((r>>3)&1) holds 8 bf16 (k = ..8g..8g+7).
__device__ __forceinline__ int frag_off(int r, int c) {
    int K16  = r >> 4;
    int cblk = c >> 5;
    int g    = (r >> 3) & 1;
    int lane = (c & 31) + (g << 5);
    return ((K16 * 4 + cblk) << 9) + (lane << 3) + (r & 7);
}

// ---------------------------------------------------------------------------
// Small fp32 GEMM producer: out = A[16384][K] @ W[K][128]; epilogue splits
// each output into bf16 hi/lo and scatters into the fragment layout.
// K=256 (X@W1) or K=128 (hidden@[Wm|Ws], FUSED: cols 0-63 from Wa, 64-127 Wb)
// ---------------------------------------------------------------------------
template<int K, bool FUSED>
__global__ __launch_bounds__(256)
void producer_kernel(const float* __restrict__ A,
                     const float* __restrict__ W,
                     const float* __restrict__ Wa,
                     const float* __restrict__ Wb,
                     bf16_t* __restrict__ Bh,
                     bf16_t* __restrict__ Bl)
{
    __shared__ float As[32][128];   // k-major A tile: As[k][r]
    __shared__ float Wsh[32][128];  // Wsh[k][c]
    const int t    = threadIdx.x;
    const int row0 = blockIdx.x * 128;
    const int tc   = t & 15, tr = t >> 4;   // 16x16 thread grid, 8x8 outs each

    float acc[8][8];
    #pragma unroll
    for (int i = 0; i < 8; ++i)
        #pragma unroll
        for (int j = 0; j < 8; ++j) acc[i][j] = 0.f;

    const int ra = t >> 1, ks = (t & 1) << 4;   // A staging: 16 f32/thread
    const int wk = t >> 3, wc = (t & 7) << 4;   // W staging: 16 f32/thread

    for (int k0 = 0; k0 < K; k0 += 32) {
        const float* ap = A + (size_t)(row0 + ra) * K + k0 + ks;
        float4 a0 = *(const float4*)(ap);
        float4 a1 = *(const float4*)(ap + 4);
        float4 a2 = *(const float4*)(ap + 8);
        float4 a3 = *(const float4*)(ap + 12);
        float4 w0, w1, w2, w3;
        if (!FUSED) {
            const float* wp = W + (size_t)(k0 + wk) * 128 + wc;
            w0 = *(const float4*)(wp);     w1 = *(const float4*)(wp + 4);
            w2 = *(const float4*)(wp + 8); w3 = *(const float4*)(wp + 12);
        } else {
            const float* wp = (wc < 64) ? (Wa + (size_t)(k0 + wk) * 64 + wc)
                                        : (Wb + (size_t)(k0 + wk) * 64 + (wc - 64));
            w0 = *(const float4*)(wp);     w1 = *(const float4*)(wp + 4);
            w2 = *(const float4*)(wp + 8); w3 = *(const float4*)(wp + 12);
        }
        __syncthreads();   // previous iteration's compute done before overwrite
        {
            float tmp[16] = {a0.x,a0.y,a0.z,a0.w, a1.x,a1.y,a1.z,a1.w,
                             a2.x,a2.y,a2.z,a2.w, a3.x,a3.y,a3.z,a3.w};
            #pragma unroll
            for (int j = 0; j < 16; ++j) As[ks + j][ra] = tmp[j];
            *(float4*)&Wsh[wk][wc     ] = w0;
            *(float4*)&Wsh[wk][wc +  4] = w1;
            *(float4*)&Wsh[wk][wc +  8] = w2;
            *(float4*)&Wsh[wk][wc + 12] = w3;
        }
        __syncthreads();
        #pragma unroll 4
        for (int k = 0; k < 32; ++k) {
            float av[8], wv[8];
            *(float4*)&av[0] = *(const float4*)&As[k][8 * tr];
            *(float4*)&av[4] = *(const float4*)&As[k][8 * tr + 4];
            *(float4*)&wv[0] = *(const float4*)&Wsh[k][8 * tc];
            *(float4*)&wv[4] = *(const float4*)&Wsh[k][8 * tc + 4];
            #pragma unroll
            for (int i = 0; i < 8; ++i)
                #pragma unroll
                for (int j = 0; j < 8; ++j)
                    acc[i][j] = fmaf(av[i], wv[j], acc[i][j]);
        }
    }

    #pragma unroll
    for (int i = 0; i < 8; ++i) {
        int r = row0 + 8 * tr + i;
        #pragma unroll
        for (int j = 0; j < 8; ++j) {
            int c = 8 * tc + j;
            float v = acc[i][j];
            bf16_t h = (bf16_t)v;
            bf16_t l = (bf16_t)(v - (float)h);
            int off = frag_off(r, c);
            Bh[off] = h;
            Bl[off] = l;
        }
    }
}

// ---------------------------------------------------------------------------
// Big kernel: out = act(adj @ B), M=K=16384, N=128.
// grid 256 (1 block/CU), 512 thr (8 waves), block tile 64x128, wave tile 32x32.
// adj: global f32 -> regs -> split hi/lo -> XOR-swizzled double-buffered LDS.
// B: prefetched dwordx4 frags straight from global (L2-hot, coalesced).
// 3-term split MFMA: hi*hi + hi*lo + lo*hi.
// ---------------------------------------------------------------------------
template<int ACT>  // 0=none, 1=relu
__global__ __launch_bounds__(512)
void adj_gemm_kernel(const float* __restrict__ adj,
                     const bf16_t* __restrict__ Bh,
                     const bf16_t* __restrict__ Bl,
                     float* __restrict__ out)
{
    __shared__ __align__(16) bf16_t AsH[2][64 * 64];
    __shared__ __align__(16) bf16_t AsL[2][64 * 64];
    const int t    = threadIdx.x;
    const int lane = t & 63;
    const int w    = t >> 6;
    const int wr   = w >> 2, wc = w & 3;     // 2x4 wave grid
    const int row0 = blockIdx.x * 64;

    // adj staging: 8 f32/thread (row sr, k sk..sk+7)
    const int sr = t >> 3;
    const int sk = (t & 7) << 3;
    const float* aptr = adj + (size_t)(row0 + sr) * 16384 + sk;
    const int widx = ((sr << 6) + sk) ^ ((sr & 7) << 3);   // XOR swizzle (bf16 units)

    // A-frag read coords: row = 32*wr + (lane&31), k = 16*s + 8*(lane>>5)
    const int frow = (wr << 5) + (lane & 31);
    const int fg   = (lane >> 5) << 3;

    f32x16 acc;
    #pragma unroll
    for (int i = 0; i < 16; ++i) acc[i] = 0.f;

    auto loadB = [&](bf16x8* bh, bf16x8* bl, int step) {
        #pragma unroll
        for (int s = 0; s < 4; ++s) {
            int K16 = (step << 2) + s;
            size_t base = ((size_t)(K16 * 4 + wc) << 9) + (lane << 3);
            bh[s] = *(const bf16x8*)(Bh + base);
            bl[s] = *(const bf16x8*)(Bl + base);
        }
    };
    auto loadA = [&](float4& p0, float4& p1, int step) {
        const float* p = aptr + (step << 6);
        p0 = *(const float4*)(p);
        p1 = *(const float4*)(p + 4);
    };
    auto cvtWrite = [&](const float4& p0, const float4& p1, int buf) {
        float xs[8] = {p0.x, p0.y, p0.z, p0.w, p1.x, p1.y, p1.z, p1.w};
        bf16x8 hv, lv;
        #pragma unroll
        for (int i = 0; i < 8; ++i) {
            bf16_t h = (bf16_t)xs[i];
            hv[i] = h;
            lv[i] = (bf16_t)(xs[i] - (float)h);
        }
        *(bf16x8*)&AsH[buf][widx] = hv;
        *(bf16x8*)&AsL[buf][widx] = lv;
    };
    auto compute = [&](int buf, const bf16x8* bh, const bf16x8* bl) {
        #pragma unroll
        for (int s = 0; s < 4; ++s) {
            int idx = ((frow << 6) + (s << 4) + fg) ^ ((frow & 7) << 3);
            bf16x8 ah = *(const bf16x8*)&AsH[buf][idx];
            bf16x8 al = *(const bf16x8*)&AsL[buf][idx];
            acc = __builtin_amdgcn_mfma_f32_32x32x16_bf16(ah, bh[s], acc, 0, 0, 0);
            acc = __builtin_amdgcn_mfma_f32_32x32x16_bf16(ah, bl[s], acc, 0, 0, 0);
            acc = __builtin_amdgcn_mfma_f32_32x32x16_bf16(al, bh[s], acc, 0, 0, 0);
        }
    };

    bf16x8 bh0[4], bl0[4], bh1[4], bl1[4];
    float4 pa0, pa1;

    loadB(bh0, bl0, 0);
    loadA(pa0, pa1, 0);
    cvtWrite(pa0, pa1, 0);
    __syncthreads();

    for (int m = 0; m < 128; ++m) {
        const int so = 2 * m + 1;
        loadA(pa0, pa1, so);          // prefetch odd step
        loadB(bh1, bl1, so);
        compute(0, bh0, bl0);         // even step from buf0
        cvtWrite(pa0, pa1, 1);
        __syncthreads();
        if (m < 127) {
            loadA(pa0, pa1, so + 1);  // prefetch next even step
            loadB(bh0, bl0, so + 1);
        }
        compute(1, bh1, bl1);         // odd step from buf1
        if (m < 127) cvtWrite(pa0, pa1, 0);
        __syncthreads();
    }

    // C write: col = lane&31 (+32*wc), row = (q&3) + 8*(q>>2) + 4*(lane>>5)
    const int col = (wc << 5) + (lane & 31);
    const int rb  = row0 + (wr << 5) + ((lane >> 5) << 2);
    #pragma unroll
    for (int q = 0; q < 16; ++q) {
        int r = rb + (q & 3) + ((q >> 2) << 3);
        float v = acc[q];
        if (ACT == 1) v = fmaxf(v, 0.f);
        out[(size_t)r * 128 + col] = v;
    }
}

// ---------------------------------------------------------------------------
// Final: mean = Z@Wp + bp; out = noise*exp(min(logstd,10)) + mean
// T = [Z | logstd] as [16384][128] f32
// ---------------------------------------------------------------------------
__global__ __launch_bounds__(256)
void final_kernel(const float* __restrict__ T,
                  const float* __restrict__ Wp,
                  const float* __restrict__ bp,
                  const float* __restrict__ noise,
                  float* __restrict__ out)
{
    __shared__ float Wps[64][64];
    __shared__ float Ts[64][64];
    const int t = threadIdx.x;
    const int row0 = blockIdx.x * 64;
    {
        int k = t >> 2, c0 = (t & 3) << 4;
        #pragma unroll
        for (int i = 0; i < 4; ++i)
            *(float4*)&Wps[k][c0 + 4 * i] = *(const float4*)&Wp[(size_t)k * 64 + c0 + 4 * i];
        #pragma unroll
        for (int i = 0; i < 4; ++i)
            *(float4*)&Ts[k][c0 + 4 * i] =
                *(const float4*)&T[(size_t)(row0 + k) * 128 + c0 + 4 * i];
    }
    __syncthreads();

    const int r  = t >> 2;
    const int c0 = (t & 3) << 4;
    float acc[16];
    #pragma unroll
    for (int j = 0; j < 16; ++j) acc[j] = bp[c0 + j];
    for (int k = 0; k < 64; ++k) {
        float a = Ts[r][k];
        #pragma unroll
        for (int j = 0; j < 16; ++j) acc[j] = fmaf(a, Wps[k][c0 + j], acc[j]);
    }
    const int grow = row0 + r;
    #pragma unroll
    for (int j = 0; j < 16; ++j) {
        float ls = T[(size_t)grow * 128 + 64 + c0 + j];
        ls = fminf(ls, 10.0f);
        out[(size_t)grow * 64 + c0 + j] =
            noise[(size_t)grow * 64 + c0 + j] * __expf(ls) + acc[j];
    }
}

// ---------------------------------------------------------------------------
extern "C" void kernel_launch(void* const* d_in, const int* in_sizes, int n_in,
                              void* d_out, int out_size, void* d_ws, size_t ws_size,
                              hipStream_t stream) {
    const float* X     = (const float*)d_in[0];
    const float* adj   = (const float*)d_in[1];
    const float* W1    = (const float*)d_in[2];
    const float* Wm    = (const float*)d_in[3];
    const float* Wsv   = (const float*)d_in[4];
    const float* Wp    = (const float*)d_in[5];
    const float* bp    = (const float*)d_in[6];
    const float* noise = (const float*)d_in[7];
    float* out = (float*)d_out;

    char* ws = (char*)d_ws;
    bf16_t* Bh   = (bf16_t*)ws;                    // 4 MB  (16384*128 bf16)
    bf16_t* Bl   = (bf16_t*)(ws + (4u << 20));     // 4 MB
    float*  Htmp = (float*)(ws + (8u << 20));      // 8 MB hidden, reused as T

    // S1: B1 = fragsplit((X @ W1)^T)
    producer_kernel<256, false><<<128, 256, 0, stream>>>(X, W1, nullptr, nullptr, Bh, Bl);
    // S2: hidden = relu(adj @ XW1)
    adj_gemm_kernel<1><<<256, 512, 0, stream>>>(adj, Bh, Bl, Htmp);
    // S3: B2 = fragsplit((hidden @ [Wm|Ws])^T)
    producer_kernel<128, true><<<128, 256, 0, stream>>>(Htmp, nullptr, Wm, Wsv, Bh, Bl);
    // S4: T = adj @ HW   (cols 0-63 = Z, 64-127 = logstd_raw)
    adj_gemm_kernel<0><<<256, 512, 0, stream>>>(adj, Bh, Bl, Htmp);
    // S5: epilogue
    final_kernel<<<256, 256, 0, stream>>>(Htmp, Wp, bp, noise, out);
}

// Round 2
// 796.407 us; speedup vs baseline: 1.1996x; 1.1996x over previous
//
#include <hip/hip_runtime.h>

// ---------------------------------------------------------------------------
// VGAE encoder, MI355X. The two adj (16384x16384 f32, 1 GiB) GEMMs dominate.
// fp32 has no MFMA on CDNA4 -> split f32 into bf16 hi+lo, 3 MFMA terms
// (hi*hi + hi*lo + lo*hi), fp32 accumulate. Memory floor = 2 adj passes
// = ~340us @ 6.3 TB/s.
// R1 change: adj_gemm pipeline. All global loads are register-destined, so
// barriers only need lgkmcnt(0) -- NOT the vmcnt(0) drain __syncthreads emits.
// Raw s_barrier + 4-deep adj register prefetch ring keeps HBM loads in
// flight across barriers (counted vmcnt, T3/T4/T14 pattern).
// ---------------------------------------------------------------------------

typedef __bf16 bf16_t;
typedef __attribute__((ext_vector_type(8))) __bf16 bf16x8;
typedef __attribute__((ext_vector_type(16))) float f32x16;

#define N_NODES 16384

// Fragment layout for the B operand of mfma_f32_32x32x16_bf16:
// element (k=r, col=c) -> 1KiB units indexed by (K16 = r>>4, cblk = c>>5),
// within a unit: lane = (c&31) + 32*((r>>3)&1) holds 8 bf16 (k = ..8g..8g+7).
__device__ __forceinline__ int frag_off(int r, int c) {
    int K16  = r >> 4;
    int cblk = c >> 5;
    int g    = (r >> 3) & 1;
    int lane = (c & 31) + (g << 5);
    return ((K16 * 4 + cblk) << 9) + (lane << 3) + (r & 7);
}

// ---------------------------------------------------------------------------
// Small fp32 GEMM producer: out = A[16384][K] @ W[K][128]; epilogue splits
// each output into bf16 hi/lo and scatters into the fragment layout.
// K=256 (X@W1) or K=128 (hidden@[Wm|Ws], FUSED: cols 0-63 from Wa, 64-127 Wb)
// ---------------------------------------------------------------------------
template<int K, bool FUSED>
__global__ __launch_bounds__(256)
void producer_kernel(const float* __restrict__ A,
                     const float* __restrict__ W,
                     const float* __restrict__ Wa,
                     const float* __restrict__ Wb,
                     bf16_t* __restrict__ Bh,
                     bf16_t* __restrict__ Bl)
{
    __shared__ float As[32][128];   // k-major A tile: As[k][r]
    __shared__ float Wsh[32][128];  // Wsh[k][c]
    const int t    = threadIdx.x;
    const int row0 = blockIdx.x * 128;
    const int tc   = t & 15, tr = t >> 4;   // 16x16 thread grid, 8x8 outs each

    float acc[8][8];
    #pragma unroll
    for (int i = 0; i < 8; ++i)
        #pragma unroll
        for (int j = 0; j < 8; ++j) acc[i][j] = 0.f;

    const int ra = t >> 1, ks = (t & 1) << 4;   // A staging: 16 f32/thread
    const int wk = t >> 3, wc = (t & 7) << 4;   // W staging: 16 f32/thread

    for (int k0 = 0; k0 < K; k0 += 32) {
        const float* ap = A + (size_t)(row0 + ra) * K + k0 + ks;
        float4 a0 = *(const float4*)(ap);
        float4 a1 = *(const float4*)(ap + 4);
        float4 a2 = *(const float4*)(ap + 8);
        float4 a3 = *(const float4*)(ap + 12);
        float4 w0, w1, w2, w3;
        if (!FUSED) {
            const float* wp = W + (size_t)(k0 + wk) * 128 + wc;
            w0 = *(const float4*)(wp);     w1 = *(const float4*)(wp + 4);
            w2 = *(const float4*)(wp + 8); w3 = *(const float4*)(wp + 12);
        } else {
            const float* wp = (wc < 64) ? (Wa + (size_t)(k0 + wk) * 64 + wc)
                                        : (Wb + (size_t)(k0 + wk) * 64 + (wc - 64));
            w0 = *(const float4*)(wp);     w1 = *(const float4*)(wp + 4);
            w2 = *(const float4*)(wp + 8); w3 = *(const float4*)(wp + 12);
        }
        __syncthreads();   // previous iteration's compute done before overwrite
        {
            float tmp[16] = {a0.x,a0.y,a0.z,a0.w, a1.x,a1.y,a1.z,a1.w,
                             a2.x,a2.y,a2.z,a2.w, a3.x,a3.y,a3.z,a3.w};
            #pragma unroll
            for (int j = 0; j < 16; ++j) As[ks + j][ra] = tmp[j];
            *(float4*)&Wsh[wk][wc     ] = w0;
            *(float4*)&Wsh[wk][wc +  4] = w1;
            *(float4*)&Wsh[wk][wc +  8] = w2;
            *(float4*)&Wsh[wk][wc + 12] = w3;
        }
        __syncthreads();
        #pragma unroll 4
        for (int k = 0; k < 32; ++k) {
            float av[8], wv[8];
            *(float4*)&av[0] = *(const float4*)&As[k][8 * tr];
            *(float4*)&av[4] = *(const float4*)&As[k][8 * tr + 4];
            *(float4*)&wv[0] = *(const float4*)&Wsh[k][8 * tc];
            *(float4*)&wv[4] = *(const float4*)&Wsh[k][8 * tc + 4];
            #pragma unroll
            for (int i = 0; i < 8; ++i)
                #pragma unroll
                for (int j = 0; j < 8; ++j)
                    acc[i][j] = fmaf(av[i], wv[j], acc[i][j]);
        }
    }

    #pragma unroll
    for (int i = 0; i < 8; ++i) {
        int r = row0 + 8 * tr + i;
        #pragma unroll
        for (int j = 0; j < 8; ++j) {
            int c = 8 * tc + j;
            float v = acc[i][j];
            bf16_t h = (bf16_t)v;
            bf16_t l = (bf16_t)(v - (float)h);
            int off = frag_off(r, c);
            Bh[off] = h;
            Bl[off] = l;
        }
    }
}

// ---------------------------------------------------------------------------
// Big kernel: out = act(adj @ B), M=K=16384, N=128.
// grid 256 (1 block/CU), 512 thr (8 waves), block tile 64x128, wave tile 32x32.
// Pipelined: 4-deep adj register-prefetch ring, double-buffered B frags,
// 2 LDS buffers, ONE raw barrier per 64-K step with lgkmcnt(0) only
// (register-destined global loads need no vmcnt drain for cross-wave
// visibility -> compiler emits counted vmcnt, loads span barriers).
// ---------------------------------------------------------------------------
template<int ACT>  // 0=none, 1=relu
__global__ __launch_bounds__(512)
void adj_gemm_kernel(const float* __restrict__ adj,
                     const bf16_t* __restrict__ Bh,
                     const bf16_t* __restrict__ Bl,
                     float* __restrict__ out)
{
    __shared__ __align__(16) bf16_t AsH[2][64 * 64];
    __shared__ __align__(16) bf16_t AsL[2][64 * 64];
    const int t    = threadIdx.x;
    const int lane = t & 63;
    const int w    = t >> 6;
    const int wr   = w >> 2, wc = w & 3;     // 2x4 wave grid
    const int row0 = blockIdx.x * 64;

    // adj staging: 8 f32/thread (row sr, k sk..sk+7)
    const int sr = t >> 3;
    const int sk = (t & 7) << 3;
    const float* aptr = adj + (size_t)(row0 + sr) * 16384 + sk;
    const int widx = ((sr << 6) + sk) ^ ((sr & 7) << 3);   // XOR swizzle (bf16 units)

    // A-frag read coords: row = 32*wr + (lane&31), k = 16*s + 8*(lane>>5)
    const int frow = (wr << 5) + (lane & 31);
    const int fg   = (lane >> 5) << 3;

    f32x16 acc;
    #pragma unroll
    for (int i = 0; i < 16; ++i) acc[i] = 0.f;

    auto loadB = [&](bf16x8* bh, bf16x8* bl, int step) {
        #pragma unroll
        for (int s = 0; s < 4; ++s) {
            int K16 = (step << 2) + s;
            size_t base = ((size_t)(K16 * 4 + wc) << 9) + (lane << 3);
            bh[s] = *(const bf16x8*)(Bh + base);
            bl[s] = *(const bf16x8*)(Bl + base);
        }
    };
    auto loadA = [&](float4& p0, float4& p1, int step) {
        const float* p = aptr + (step << 6);
        p0 = *(const float4*)(p);
        p1 = *(const float4*)(p + 4);
    };
    auto cvtWrite = [&](const float4& p0, const float4& p1, int buf) {
        float xs[8] = {p0.x, p0.y, p0.z, p0.w, p1.x, p1.y, p1.z, p1.w};
        bf16x8 hv, lv;
        #pragma unroll
        for (int i = 0; i < 8; ++i) {
            bf16_t h = (bf16_t)xs[i];
            hv[i] = h;
            lv[i] = (bf16_t)(xs[i] - (float)h);
        }
        *(bf16x8*)&AsH[buf][widx] = hv;
        *(bf16x8*)&AsL[buf][widx] = lv;
    };
    auto compute = [&](int buf, const bf16x8* bh, const bf16x8* bl) {
        #pragma unroll
        for (int s = 0; s < 4; ++s) {
            int idx = ((frow << 6) + (s << 4) + fg) ^ ((frow & 7) << 3);
            bf16x8 ah = *(const bf16x8*)&AsH[buf][idx];
            bf16x8 al = *(const bf16x8*)&AsL[buf][idx];
            acc = __builtin_amdgcn_mfma_f32_32x32x16_bf16(ah, bh[s], acc, 0, 0, 0);
            acc = __builtin_amdgcn_mfma_f32_32x32x16_bf16(ah, bl[s], acc, 0, 0, 0);
            acc = __builtin_amdgcn_mfma_f32_32x32x16_bf16(al, bh[s], acc, 0, 0, 0);
        }
    };

    // lgkmcnt(0)-only barrier: ds ops drained, global (register-dest) loads
    // stay in flight across the barrier (counted vmcnt by compiler).
#define SYNC_LDS() do { asm volatile("s_waitcnt lgkmcnt(0)" ::: "memory"); \
                        __builtin_amdgcn_s_barrier(); } while (0)

    float4 paA[4], paB[4];             // 4-deep adj prefetch ring (literal idx)
    bf16x8 bhA[4], blA[4], bhB[4], blB[4];

    // -------- prologue: fill the ring, stage step 0 --------
    loadA(paA[0], paB[0], 0);
    loadA(paA[1], paB[1], 1);
    loadA(paA[2], paB[2], 2);
    loadA(paA[3], paB[3], 3);
    loadB(bhA, blA, 0);
    cvtWrite(paA[0], paB[0], 0);
    SYNC_LDS();

    // steady-state body: step i = i0 + k (k literal 0..3)
    //  pre: buf[k&1] holds step i; cur B-set holds step i; ring slots hold
    //       steps i+1..i+3 (in flight).
#define BODY(k, CH, CL, NH, NL) do {                                        \
        loadA(paA[(k)], paB[(k)], i0 + (k) + 4);   /* deepest prefetch   */ \
        loadB(NH, NL, i0 + (k) + 1);               /* next-step B frags  */ \
        compute((k) & 1, CH, CL);                                           \
        cvtWrite(paA[((k) + 1) & 3], paB[((k) + 1) & 3], ((k) + 1) & 1);    \
        SYNC_LDS();                                                         \
    } while (0)

    for (int i0 = 0; i0 < 252; i0 += 4) {
        BODY(0, bhA, blA, bhB, blB);
        BODY(1, bhB, blB, bhA, blA);
        BODY(2, bhA, blA, bhB, blB);
        BODY(3, bhB, blB, bhA, blA);
    }
#undef BODY

    // -------- epilogue: steps 252..255, no further loadA --------
    // i = 252 (cur = A-set, buf 0)
    loadB(bhB, blB, 253);
    compute(0, bhA, blA);
    cvtWrite(paA[1], paB[1], 1);
    SYNC_LDS();
    // i = 253
    loadB(bhA, blA, 254);
    compute(1, bhB, blB);
    cvtWrite(paA[2], paB[2], 0);
    SYNC_LDS();
    // i = 254
    loadB(bhB, blB, 255);
    compute(0, bhA, blA);
    cvtWrite(paA[3], paB[3], 1);
    SYNC_LDS();
    // i = 255
    compute(1, bhB, blB);
#undef SYNC_LDS

    // C write: col = lane&31 (+32*wc), row = (q&3) + 8*(q>>2) + 4*(lane>>5)
    const int col = (wc << 5) + (lane & 31);
    const int rb  = row0 + (wr << 5) + ((lane >> 5) << 2);
    #pragma unroll
    for (int q = 0; q < 16; ++q) {
        int r = rb + (q & 3) + ((q >> 2) << 3);
        float v = acc[q];
        if (ACT == 1) v = fmaxf(v, 0.f);
        out[(size_t)r * 128 + col] = v;
    }
}

// ---------------------------------------------------------------------------
// Final: mean = Z@Wp + bp; out = noise*exp(min(logstd,10)) + mean
// T = [Z | logstd] as [16384][128] f32
// ---------------------------------------------------------------------------
__global__ __launch_bounds__(256)
void final_kernel(const float* __restrict__ T,
                  const float* __restrict__ Wp,
                  const float* __restrict__ bp,
                  const float* __restrict__ noise,
                  float* __restrict__ out)
{
    __shared__ float Wps[64][64];
    __shared__ float Ts[64][64];
    const int t = threadIdx.x;
    const int row0 = blockIdx.x * 64;
    {
        int k = t >> 2, c0 = (t & 3) << 4;
        #pragma unroll
        for (int i = 0; i < 4; ++i)
            *(float4*)&Wps[k][c0 + 4 * i] = *(const float4*)&Wp[(size_t)k * 64 + c0 + 4 * i];
        #pragma unroll
        for (int i = 0; i < 4; ++i)
            *(float4*)&Ts[k][c0 + 4 * i] =
                *(const float4*)&T[(size_t)(row0 + k) * 128 + c0 + 4 * i];
    }
    __syncthreads();

    const int r  = t >> 2;
    const int c0 = (t & 3) << 4;
    float acc[16];
    #pragma unroll
    for (int j = 0; j < 16; ++j) acc[j] = bp[c0 + j];
    for (int k = 0; k < 64; ++k) {
        float a = Ts[r][k];
        #pragma unroll
        for (int j = 0; j < 16; ++j) acc[j] = fmaf(a, Wps[k][c0 + j], acc[j]);
    }
    const int grow = row0 + r;
    #pragma unroll
    for (int j = 0; j < 16; ++j) {
        float ls = T[(size_t)grow * 128 + 64 + c0 + j];
        ls = fminf(ls, 10.0f);
        out[(size_t)grow * 64 + c0 + j] =
            noise[(size_t)grow * 64 + c0 + j] * __expf(ls) + acc[j];
    }
}

// ---------------------------------------------------------------------------
extern "C" void kernel_launch(void* const* d_in, const int* in_sizes, int n_in,
                              void* d_out, int out_size, void* d_ws, size_t ws_size,
                              hipStream_t stream) {
    const float* X     = (const float*)d_in[0];
    const float* adj   = (const float*)d_in[1];
    const float* W1    = (const float*)d_in[2];
    const float* Wm    = (const float*)d_in[3];
    const float* Wsv   = (const float*)d_in[4];
    const float* Wp    = (const float*)d_in[5];
    const float* bp    = (const float*)d_in[6];
    const float* noise = (const float*)d_in[7];
    float* out = (float*)d_out;

    char* ws = (char*)d_ws;
    bf16_t* Bh   = (bf16_t*)ws;                    // 4 MB  (16384*128 bf16)
    bf16_t* Bl   = (bf16_t*)(ws + (4u << 20));     // 4 MB
    float*  Htmp = (float*)(ws + (8u << 20));      // 8 MB hidden, reused as T

    // S1: B1 = fragsplit((X @ W1)^T)
    producer_kernel<256, false><<<128, 256, 0, stream>>>(X, W1, nullptr, nullptr, Bh, Bl);
    // S2: hidden = relu(adj @ XW1)
    adj_gemm_kernel<1><<<256, 512, 0, stream>>>(adj, Bh, Bl, Htmp);
    // S3: B2 = fragsplit((hidden @ [Wm|Ws])^T)
    producer_kernel<128, true><<<128, 256, 0, stream>>>(Htmp, nullptr, Wm, Wsv, Bh, Bl);
    // S4: T = adj @ HW   (cols 0-63 = Z, 64-127 = logstd_raw)
    adj_gemm_kernel<0><<<256, 512, 0, stream>>>(adj, Bh, Bl, Htmp);
    // S5: epilogue
    final_kernel<<<256, 256, 0, stream>>>(Htmp, Wp, bp, noise, out);
}

// Round 3
// 783.110 us; speedup vs baseline: 1.2200x; 1.0170x over previous
//
#include <hip/hip_runtime.h>

// ---------------------------------------------------------------------------
// VGAE encoder, MI355X. The two adj (16384x16384 f32, 1 GiB) GEMMs dominate.
// fp32 has no MFMA on CDNA4 -> split f32 into bf16 hi+lo, 3 MFMA terms
// (hi*hi + hi*lo + lo*hi), fp32 accumulate. Memory floor = 2 adj passes
// = ~340us @ 6.3 TB/s.
// R2: counted-vmcnt barriers (lgkmcnt(0)-only) + 4-deep adj reg ring.
// R3: fix the in-order-vmcnt pitfall -- B prefetched 2 steps deep (4 reg
// sets), loadB issued BEFORE loadA so waits never force the newest loads;
// nontemporal adj loads to keep the B working set resident in L2.
// ---------------------------------------------------------------------------

typedef __bf16 bf16_t;
typedef __attribute__((ext_vector_type(8))) __bf16 bf16x8;
typedef __attribute__((ext_vector_type(16))) float f32x16;
typedef __attribute__((ext_vector_type(4)))  float f32x4;

#define N_NODES 16384

// Fragment layout for the B operand of mfma_f32_32x32x16_bf16:
// element (k=r, col=c) -> 1KiB units indexed by (K16 = r>>4, cblk = c>>5),
// within a unit: lane = (c&31) + 32*((r>>3)&1) holds 8 bf16 (k = ..8g..8g+7).
__device__ __forceinline__ int frag_off(int r, int c) {
    int K16  = r >> 4;
    int cblk = c >> 5;
    int g    = (r >> 3) & 1;
    int lane = (c & 31) + (g << 5);
    return ((K16 * 4 + cblk) << 9) + (lane << 3) + (r & 7);
}

// ---------------------------------------------------------------------------
// Small fp32 GEMM producer: out = A[16384][K] @ W[K][128]; epilogue splits
// each output into bf16 hi/lo and scatters into the fragment layout.
// K=256 (X@W1) or K=128 (hidden@[Wm|Ws], FUSED: cols 0-63 from Wa, 64-127 Wb)
// ---------------------------------------------------------------------------
template<int K, bool FUSED>
__global__ __launch_bounds__(256)
void producer_kernel(const float* __restrict__ A,
                     const float* __restrict__ W,
                     const float* __restrict__ Wa,
                     const float* __restrict__ Wb,
                     bf16_t* __restrict__ Bh,
                     bf16_t* __restrict__ Bl)
{
    __shared__ float As[32][128];   // k-major A tile: As[k][r]
    __shared__ float Wsh[32][128];  // Wsh[k][c]
    const int t    = threadIdx.x;
    const int row0 = blockIdx.x * 128;
    const int tc   = t & 15, tr = t >> 4;   // 16x16 thread grid, 8x8 outs each

    float acc[8][8];
    #pragma unroll
    for (int i = 0; i < 8; ++i)
        #pragma unroll
        for (int j = 0; j < 8; ++j) acc[i][j] = 0.f;

    const int ra = t >> 1, ks = (t & 1) << 4;   // A staging: 16 f32/thread
    const int wk = t >> 3, wc = (t & 7) << 4;   // W staging: 16 f32/thread

    for (int k0 = 0; k0 < K; k0 += 32) {
        const float* ap = A + (size_t)(row0 + ra) * K + k0 + ks;
        float4 a0 = *(const float4*)(ap);
        float4 a1 = *(const float4*)(ap + 4);
        float4 a2 = *(const float4*)(ap + 8);
        float4 a3 = *(const float4*)(ap + 12);
        float4 w0, w1, w2, w3;
        if (!FUSED) {
            const float* wp = W + (size_t)(k0 + wk) * 128 + wc;
            w0 = *(const float4*)(wp);     w1 = *(const float4*)(wp + 4);
            w2 = *(const float4*)(wp + 8); w3 = *(const float4*)(wp + 12);
        } else {
            const float* wp = (wc < 64) ? (Wa + (size_t)(k0 + wk) * 64 + wc)
                                        : (Wb + (size_t)(k0 + wk) * 64 + (wc - 64));
            w0 = *(const float4*)(wp);     w1 = *(const float4*)(wp + 4);
            w2 = *(const float4*)(wp + 8); w3 = *(const float4*)(wp + 12);
        }
        __syncthreads();   // previous iteration's compute done before overwrite
        {
            float tmp[16] = {a0.x,a0.y,a0.z,a0.w, a1.x,a1.y,a1.z,a1.w,
                             a2.x,a2.y,a2.z,a2.w, a3.x,a3.y,a3.z,a3.w};
            #pragma unroll
            for (int j = 0; j < 16; ++j) As[ks + j][ra] = tmp[j];
            *(float4*)&Wsh[wk][wc     ] = w0;
            *(float4*)&Wsh[wk][wc +  4] = w1;
            *(float4*)&Wsh[wk][wc +  8] = w2;
            *(float4*)&Wsh[wk][wc + 12] = w3;
        }
        __syncthreads();
        #pragma unroll 4
        for (int k = 0; k < 32; ++k) {
            float av[8], wv[8];
            *(float4*)&av[0] = *(const float4*)&As[k][8 * tr];
            *(float4*)&av[4] = *(const float4*)&As[k][8 * tr + 4];
            *(float4*)&wv[0] = *(const float4*)&Wsh[k][8 * tc];
            *(float4*)&wv[4] = *(const float4*)&Wsh[k][8 * tc + 4];
            #pragma unroll
            for (int i = 0; i < 8; ++i)
                #pragma unroll
                for (int j = 0; j < 8; ++j)
                    acc[i][j] = fmaf(av[i], wv[j], acc[i][j]);
        }
    }

    #pragma unroll
    for (int i = 0; i < 8; ++i) {
        int r = row0 + 8 * tr + i;
        #pragma unroll
        for (int j = 0; j < 8; ++j) {
            int c = 8 * tc + j;
            float v = acc[i][j];
            bf16_t h = (bf16_t)v;
            bf16_t l = (bf16_t)(v - (float)h);
            int off = frag_off(r, c);
            Bh[off] = h;
            Bl[off] = l;
        }
    }
}

// ---------------------------------------------------------------------------
// Big kernel: out = act(adj @ B), M=K=16384, N=128.
// grid 256 (1 block/CU), 512 thr (8 waves), block tile 64x128, wave tile 32x32.
// Pipeline: B frags 2 steps deep (4 register sets), adj 4 steps deep (reg
// ring), loadB issued BEFORE loadA so in-order vmcnt waits never force the
// newest loads. One raw barrier per step, lgkmcnt(0) only. Nontemporal adj.
// ---------------------------------------------------------------------------
template<int ACT>  // 0=none, 1=relu
__global__ __launch_bounds__(512, 2)
void adj_gemm_kernel(const float* __restrict__ adj,
                     const bf16_t* __restrict__ Bh,
                     const bf16_t* __restrict__ Bl,
                     float* __restrict__ out)
{
    __shared__ __align__(16) bf16_t AsH[2][64 * 64];
    __shared__ __align__(16) bf16_t AsL[2][64 * 64];
    const int t    = threadIdx.x;
    const int lane = t & 63;
    const int w    = t >> 6;
    const int wr   = w >> 2, wc = w & 3;     // 2x4 wave grid
    const int row0 = blockIdx.x * 64;

    // adj staging: 8 f32/thread (row sr, k sk..sk+7)
    const int sr = t >> 3;
    const int sk = (t & 7) << 3;
    const float* aptr = adj + (size_t)(row0 + sr) * 16384 + sk;
    const int widx = ((sr << 6) + sk) ^ ((sr & 7) << 3);   // XOR swizzle (bf16 units)
    bf16_t* const wH0 = &AsH[0][widx]; bf16_t* const wH1 = &AsH[1][widx];
    bf16_t* const wL0 = &AsL[0][widx]; bf16_t* const wL1 = &AsL[1][widx];

    // A-frag read coords: row = 32*wr + (lane&31), k = 16*s + 8*(lane>>5)
    const int frow = (wr << 5) + (lane & 31);
    const int fg   = (lane >> 5) << 3;
    int ridx[4];
    #pragma unroll
    for (int s = 0; s < 4; ++s)
        ridx[s] = ((frow << 6) + (s << 4) + fg) ^ ((frow & 7) << 3);

    // B frag per-thread base (bf16 elements); step stride = 8192 elements
    const int tb = (wc << 9) + (lane << 3);

    f32x16 acc;
    #pragma unroll
    for (int i = 0; i < 16; ++i) acc[i] = 0.f;

    auto loadB = [&](bf16x8* bh, bf16x8* bl, int step) {
        const size_t base = ((size_t)step << 13) + tb;
        #pragma unroll
        for (int s = 0; s < 4; ++s) {
            bh[s] = *(const bf16x8*)(Bh + base + (s << 11));
            bl[s] = *(const bf16x8*)(Bl + base + (s << 11));
        }
    };
    auto loadA = [&](f32x4& p0, f32x4& p1, int step) {
        const f32x4* p = (const f32x4*)(aptr + (step << 6));
        p0 = __builtin_nontemporal_load(p);
        p1 = __builtin_nontemporal_load(p + 1);
    };
    auto cvtWrite = [&](const f32x4& p0, const f32x4& p1, int buf) {
        float xs[8] = {p0[0], p0[1], p0[2], p0[3], p1[0], p1[1], p1[2], p1[3]};
        bf16x8 hv, lv;
        #pragma unroll
        for (int i = 0; i < 8; ++i) {
            bf16_t h = (bf16_t)xs[i];
            hv[i] = h;
            lv[i] = (bf16_t)(xs[i] - (float)h);
        }
        *(bf16x8*)(buf ? wH1 : wH0) = hv;
        *(bf16x8*)(buf ? wL1 : wL0) = lv;
    };
    auto compute = [&](int buf, const bf16x8* bh, const bf16x8* bl) {
        #pragma unroll
        for (int s = 0; s < 4; ++s) {
            const bf16_t* baseH = buf ? &AsH[1][0] : &AsH[0][0];
            const bf16_t* baseL = buf ? &AsL[1][0] : &AsL[0][0];
            bf16x8 ah = *(const bf16x8*)(baseH + ridx[s]);
            bf16x8 al = *(const bf16x8*)(baseL + ridx[s]);
            acc = __builtin_amdgcn_mfma_f32_32x32x16_bf16(ah, bh[s], acc, 0, 0, 0);
            acc = __builtin_amdgcn_mfma_f32_32x32x16_bf16(ah, bl[s], acc, 0, 0, 0);
            acc = __builtin_amdgcn_mfma_f32_32x32x16_bf16(al, bh[s], acc, 0, 0, 0);
        }
    };

    // lgkmcnt(0)-only barrier: ds ops drained, global (register-dest) loads
    // stay in flight across the barrier (counted vmcnt by compiler).
#define SYNC_LDS() do { asm volatile("s_waitcnt lgkmcnt(0)" ::: "memory"); \
                        __builtin_amdgcn_s_barrier(); } while (0)

    f32x4 paA[4], paB[4];                 // 4-deep adj prefetch ring
    bf16x8 bhS0[4], blS0[4], bhS1[4], blS1[4];   // 4 B sets: 2-step prefetch
    bf16x8 bhS2[4], blS2[4], bhS3[4], blS3[4];

    // -------- prologue --------
    loadA(paA[0], paB[0], 0);
    loadA(paA[1], paB[1], 1);
    loadA(paA[2], paB[2], 2);
    loadA(paA[3], paB[3], 3);
    loadB(bhS0, blS0, 0);
    loadB(bhS1, blS1, 1);
    cvtWrite(paA[0], paB[0], 0);
    SYNC_LDS();

    // steady state: step i = i0 + k.  Set k&3 holds B(i); prefetch B(i+2)
    // into set (k+2)&3 FIRST (so vmcnt waits keep 2 steps in flight); then
    // adj(i+4) into ring slot k; compute; stage adj(i+1); barrier.
#define BODY(k, CH, CL, PH, PL) do {                                        \
        loadB(PH, PL, i0 + (k) + 2);                                        \
        loadA(paA[(k)], paB[(k)], i0 + (k) + 4);                            \
        compute((k) & 1, CH, CL);                                           \
        cvtWrite(paA[((k) + 1) & 3], paB[((k) + 1) & 3], ((k) + 1) & 1);    \
        SYNC_LDS();                                                         \
    } while (0)

    for (int i0 = 0; i0 < 252; i0 += 4) {
        BODY(0, bhS0, blS0, bhS2, blS2);
        BODY(1, bhS1, blS1, bhS3, blS3);
        BODY(2, bhS2, blS2, bhS0, blS0);
        BODY(3, bhS3, blS3, bhS1, blS1);
    }
#undef BODY

    // -------- epilogue: steps 252..255 --------
    // state: S0=B252, S1=B253; ring slots 0..3 = adj 252..255; buf0 staged 252
    loadB(bhS2, blS2, 254);
    compute(0, bhS0, blS0);
    cvtWrite(paA[1], paB[1], 1);          // adj 253
    SYNC_LDS();
    loadB(bhS3, blS3, 255);
    compute(1, bhS1, blS1);
    cvtWrite(paA[2], paB[2], 0);          // adj 254
    SYNC_LDS();
    compute(0, bhS2, blS2);
    cvtWrite(paA[3], paB[3], 1);          // adj 255
    SYNC_LDS();
    compute(1, bhS3, blS3);
#undef SYNC_LDS

    // C write: col = lane&31 (+32*wc), row = (q&3) + 8*(q>>2) + 4*(lane>>5)
    const int col = (wc << 5) + (lane & 31);
    const int rb  = row0 + (wr << 5) + ((lane >> 5) << 2);
    #pragma unroll
    for (int q = 0; q < 16; ++q) {
        int r = rb + (q & 3) + ((q >> 2) << 3);
        float v = acc[q];
        if (ACT == 1) v = fmaxf(v, 0.f);
        out[(size_t)r * 128 + col] = v;
    }
}

// ---------------------------------------------------------------------------
// Final: mean = Z@Wp + bp; out = noise*exp(min(logstd,10)) + mean
// T = [Z | logstd] as [16384][128] f32
// ---------------------------------------------------------------------------
__global__ __launch_bounds__(256)
void final_kernel(const float* __restrict__ T,
                  const float* __restrict__ Wp,
                  const float* __restrict__ bp,
                  const float* __restrict__ noise,
                  float* __restrict__ out)
{
    __shared__ float Wps[64][64];
    __shared__ float Ts[64][64];
    const int t = threadIdx.x;
    const int row0 = blockIdx.x * 64;
    {
        int k = t >> 2, c0 = (t & 3) << 4;
        #pragma unroll
        for (int i = 0; i < 4; ++i)
            *(float4*)&Wps[k][c0 + 4 * i] = *(const float4*)&Wp[(size_t)k * 64 + c0 + 4 * i];
        #pragma unroll
        for (int i = 0; i < 4; ++i)
            *(float4*)&Ts[k][c0 + 4 * i] =
                *(const float4*)&T[(size_t)(row0 + k) * 128 + c0 + 4 * i];
    }
    __syncthreads();

    const int r  = t >> 2;
    const int c0 = (t & 3) << 4;
    float acc[16];
    #pragma unroll
    for (int j = 0; j < 16; ++j) acc[j] = bp[c0 + j];
    for (int k = 0; k < 64; ++k) {
        float a = Ts[r][k];
        #pragma unroll
        for (int j = 0; j < 16; ++j) acc[j] = fmaf(a, Wps[k][c0 + j], acc[j]);
    }
    const int grow = row0 + r;
    #pragma unroll
    for (int j = 0; j < 16; ++j) {
        float ls = T[(size_t)grow * 128 + 64 + c0 + j];
        ls = fminf(ls, 10.0f);
        out[(size_t)grow * 64 + c0 + j] =
            noise[(size_t)grow * 64 + c0 + j] * __expf(ls) + acc[j];
    }
}

// ---------------------------------------------------------------------------
extern "C" void kernel_launch(void* const* d_in, const int* in_sizes, int n_in,
                              void* d_out, int out_size, void* d_ws, size_t ws_size,
                              hipStream_t stream) {
    const float* X     = (const float*)d_in[0];
    const float* adj   = (const float*)d_in[1];
    const float* W1    = (const float*)d_in[2];
    const float* Wm    = (const float*)d_in[3];
    const float* Wsv   = (const float*)d_in[4];
    const float* Wp    = (const float*)d_in[5];
    const float* bp    = (const float*)d_in[6];
    const float* noise = (const float*)d_in[7];
    float* out = (float*)d_out;

    char* ws = (char*)d_ws;
    bf16_t* Bh   = (bf16_t*)ws;                    // 4 MB  (16384*128 bf16)
    bf16_t* Bl   = (bf16_t*)(ws + (4u << 20));     // 4 MB
    float*  Htmp = (float*)(ws + (8u << 20));      // 8 MB hidden, reused as T

    // S1: B1 = fragsplit((X @ W1)^T)
    producer_kernel<256, false><<<128, 256, 0, stream>>>(X, W1, nullptr, nullptr, Bh, Bl);
    // S2: hidden = relu(adj @ XW1)
    adj_gemm_kernel<1><<<256, 512, 0, stream>>>(adj, Bh, Bl, Htmp);
    // S3: B2 = fragsplit((hidden @ [Wm|Ws])^T)
    producer_kernel<128, true><<<128, 256, 0, stream>>>(Htmp, nullptr, Wm, Wsv, Bh, Bl);
    // S4: T = adj @ HW   (cols 0-63 = Z, 64-127 = logstd_raw)
    adj_gemm_kernel<0><<<256, 512, 0, stream>>>(adj, Bh, Bl, Htmp);
    // S5: epilogue
    final_kernel<<<256, 256, 0, stream>>>(Htmp, Wp, bp, noise, out);
}